// Round 20
// baseline (199.572 us; speedup 1.0000x reference)
//
#include <hip/hip_runtime.h>
#include <hip/hip_bf16.h>
#include <math.h>

#define B_G   128
#define N0    512
#define DEG   8
#define CCH   128
#define EPG   (N0*DEG)            // 4096 edges per graph (fixed slab)
#define E_TOTAL (B_G*EPG)
#define K1    410
#define K2    328
#define K3    263
#define NCLS  10

// swizzled float4-block offset within a 32-float row: kills 8-way bank conflicts
#define SWZ(row, cb) ((((cb) ^ ((row) & 7)) << 2))

using bf16x8 = __attribute__((ext_vector_type(8))) __bf16;
using f32x4  = __attribute__((ext_vector_type(4))) float;
typedef unsigned short ushort;
typedef unsigned int uint;
typedef unsigned long long u64;

__device__ __forceinline__ ushort f2b(float f) {
    uint u = __float_as_uint(f);
    u += 0x7fffu + ((u >> 16) & 1u);      // RNE
    return (ushort)(u >> 16);
}
__device__ __forceinline__ float b2f(ushort h) {
    return __uint_as_float(((uint)h) << 16);
}
__device__ __forceinline__ void split2(float v, ushort& hi, ushort& lo) {
    hi = f2b(v);
    lo = f2b(v - b2f(hi));
}
__device__ __forceinline__ uint pksplit(float v) {
    ushort h, l; split2(v, h, l);
    return (uint)h | ((uint)l << 16);
}
__device__ __forceinline__ float unpk(uint u) {
    return __uint_as_float(u << 16) + __uint_as_float(u & 0xffff0000u);
}
__device__ __forceinline__ float keyval(u64 key) {
    uint tu = (uint)(key >> 32);
    uint su = (tu & 0x80000000u) ? (tu & 0x7fffffffu) : ~tu;
    return __uint_as_float(su);
}

// ---------------- setup: layer-0 CSR (blocks 0..B_G-1) | pack weights ----------------
__global__ __launch_bounds__(512) void setup_kernel(
        const float* __restrict__ Wrel0, const float* __restrict__ Wroot0,
        const float* __restrict__ Wrel1, const float* __restrict__ Wroot1,
        const float* __restrict__ Wrel2, const float* __restrict__ Wroot2,
        ushort* __restrict__ Bph, ushort* __restrict__ Bpl,
        const int* __restrict__ es, const int* __restrict__ ed,
        int* __restrict__ indptr0, int* __restrict__ counts0, ushort* __restrict__ srclist0) {
    __shared__ uint epk[EPG];     // 16 KB
    __shared__ int cnt[512], pref[512], curs[512];
    if (blockIdx.x < B_G) {
        int b = blockIdx.x, tid = threadIdx.x;
        cnt[tid] = 0;
        __syncthreads();
        int base = b * EPG;
        for (int i = tid; i < EPG; i += 512) {
            int s = es[base + i] & (N0 - 1);
            int d = ed[base + i] & (N0 - 1);
            epk[i] = (uint)s | ((uint)d << 16);
            atomicAdd(&cnt[d], 1);
        }
        __syncthreads();
        pref[tid] = cnt[tid];
        __syncthreads();
        for (int off = 1; off < 512; off <<= 1) {
            int v = (tid >= off) ? pref[tid - off] : 0;
            __syncthreads();
            pref[tid] += v;
            __syncthreads();
        }
        int excl = tid ? pref[tid - 1] : 0;
        indptr0[b * N0 + tid] = base + excl;
        counts0[b * N0 + tid] = cnt[tid];
        curs[tid] = excl;
        __syncthreads();
        for (int i = tid; i < EPG; i += 512) {
            uint wv = epk[i];
            int dl = wv >> 16;
            int pos = atomicAdd(&curs[dl], 1);
            srclist0[base + pos] = (ushort)(wv & 0xFFFFu);
        }
    } else {
        int i = (blockIdx.x - B_G) * 512 + threadIdx.x;
        if (i < 3 * 32768) {
            int layer = i >> 15, rem = i & 32767;
            int j = rem & 7, lane = (rem >> 3) & 63, cf = (rem >> 9) & 7, ks = rem >> 12;
            int k = ks * 32 + (lane >> 4) * 8 + j;
            int c = cf * 16 + (lane & 15);
            const float* Wrel  = layer == 0 ? Wrel0  : layer == 1 ? Wrel1  : Wrel2;
            const float* Wroot = layer == 0 ? Wroot0 : layer == 1 ? Wroot1 : Wroot2;
            float v = (k < 128) ? Wrel[k * 128 + c] : Wroot[(k - 128) * 128 + c];
            ushort hi, lo; split2(v, hi, lo);
            Bph[i] = hi; Bpl[i] = lo;
        }
    }
}

// ---------------- layer-0 aggregation: fp32 x0 direct, swizzled LDS slab ----------------
__global__ __launch_bounds__(1024) void aggregate0(
        const float* __restrict__ xf,
        const int* __restrict__ indptr, const int* __restrict__ counts,
        const ushort* __restrict__ srclist,
        uint* __restrict__ aggp) {
    extern __shared__ float slab[];            // [512][32] fp32, column-swizzled
    int b = blockIdx.x >> 2, q = blockIdx.x & 3;
    int tid = threadIdx.x;
    const float4* xf4 = (const float4*)xf;     // row = 32 float4s
    for (int t = tid; t < N0 * 8; t += 1024) {
        int nd = t >> 3, c4 = t & 7;
        float4 u = xf4[(size_t)(b * N0 + nd) * 32 + q * 8 + c4];
        *(float4*)&slab[nd * 32 + SWZ(nd, c4)] = u;
    }
    __syncthreads();
    int wave = tid >> 6, lane = tid & 63;
    int gl = lane >> 3, sub = lane & 7;
    for (int g = wave; g < N0 / 8; g += 16) {
        int d = g * 8 + gl;
        int beg = indptr[b * N0 + d];
        int cnt = counts[b * N0 + d];
        float4 acc = make_float4(0.f, 0.f, 0.f, 0.f);
        int id_next = (cnt > 0) ? (int)srclist[beg] : 0;
        for (int j = 0; j < cnt; j++) {
            int id = id_next;
            if (j + 1 < cnt) id_next = (int)srclist[beg + j + 1];
            const float4 v = *(const float4*)&slab[id * 32 + SWZ(id, sub)];
            acc.x += v.x; acc.y += v.y; acc.z += v.z; acc.w += v.w;
        }
        uint4 o;
        o.x = pksplit(acc.x); o.y = pksplit(acc.y);
        o.z = pksplit(acc.z); o.w = pksplit(acc.w);
        *(uint4*)&aggp[(size_t)(b * N0 + d) * CCH + q * 32 + sub * 4] = o;
    }
}

// ---------------- bf16x3 MFMA transform + fused score (LDS-staged B) ----------------
__global__ __launch_bounds__(512, 4) void transform_mfma(
        const uint* __restrict__ aggp, const uint* __restrict__ rootp,
        const float* __restrict__ rootf,
        const ushort* __restrict__ Bph, const ushort* __restrict__ Bpl,
        const float* __restrict__ brel, const float* __restrict__ pvec,
        uint* __restrict__ hout, float* __restrict__ score) {
    __shared__ ushort ldsBh[16384];   // 32 KB: [4 ks][8 cf][64 lane][8]
    __shared__ ushort ldsBl[16384];   // 32 KB
    int tid = threadIdx.x;
    int wave = tid >> 6, lane = tid & 63;
    int r = lane & 15, kb = lane >> 4;
    int rows0 = blockIdx.x * 128 + wave * 16;
    int gid = rows0 + r;

    f32x4 acc[8];
#pragma unroll
    for (int cf = 0; cf < 8; cf++) acc[cf] = (f32x4)(0.f);

    union U16 { uint u[4]; bf16x8 v; };

#pragma unroll
    for (int half = 0; half < 2; half++) {
        if (half) __syncthreads();
#pragma unroll
        for (int i = 0; i < 4; i++) {
            int idx = tid + i * 512;
            ((uint4*)ldsBh)[idx] = ((const uint4*)(Bph + half * 16384))[idx];
            ((uint4*)ldsBl)[idx] = ((const uint4*)(Bpl + half * 16384))[idx];
        }
        __syncthreads();
#pragma unroll
        for (int ks4 = 0; ks4 < 4; ks4++) {
            U16 ah, al;
            if (half && rootf) {
                const float* R = rootf + (size_t)gid * CCH + ks4 * 32 + kb * 8;
                float4 f0 = *(const float4*)R;
                float4 f1 = *(const float4*)(R + 4);
                float c[8] = {f0.x, f0.y, f0.z, f0.w, f1.x, f1.y, f1.z, f1.w};
#pragma unroll
                for (int p2 = 0; p2 < 4; p2++) {
                    ushort h0, l0, h1, l1;
                    split2(c[2 * p2], h0, l0);
                    split2(c[2 * p2 + 1], h1, l1);
                    ah.u[p2] = (uint)h0 | ((uint)h1 << 16);
                    al.u[p2] = (uint)l0 | ((uint)l1 << 16);
                }
            } else {
                const uint* A = half ? rootp : aggp;
                size_t rowbase = (size_t)gid * CCH + ks4 * 32 + kb * 8;
                uint4 ua = *(const uint4*)&A[rowbase];
                uint4 ub = *(const uint4*)&A[rowbase + 4];
                ah.u[0] = (ua.x & 0xffffu) | (ua.y << 16);
                ah.u[1] = (ua.z & 0xffffu) | (ua.w << 16);
                ah.u[2] = (ub.x & 0xffffu) | (ub.y << 16);
                ah.u[3] = (ub.z & 0xffffu) | (ub.w << 16);
                al.u[0] = (ua.x >> 16) | (ua.y & 0xffff0000u);
                al.u[1] = (ua.z >> 16) | (ua.w & 0xffff0000u);
                al.u[2] = (ub.x >> 16) | (ub.y & 0xffff0000u);
                al.u[3] = (ub.z >> 16) | (ub.w & 0xffff0000u);
            }
#pragma unroll
            for (int cf = 0; cf < 8; cf++) {
                bf16x8 bh = *(const bf16x8*)&ldsBh[((ks4 * 8 + cf) * 64 + lane) * 8];
                bf16x8 bl = *(const bf16x8*)&ldsBl[((ks4 * 8 + cf) * 64 + lane) * 8];
                acc[cf] = __builtin_amdgcn_mfma_f32_16x16x32_bf16(ah.v, bl, acc[cf], 0, 0, 0);
                acc[cf] = __builtin_amdgcn_mfma_f32_16x16x32_bf16(al.v, bh, acc[cf], 0, 0, 0);
                acc[cf] = __builtin_amdgcn_mfma_f32_16x16x32_bf16(ah.v, bh, acc[cf], 0, 0, 0);
            }
        }
    }

    float pv[8], bb[8], q = 0.f;
#pragma unroll
    for (int cf = 0; cf < 8; cf++) {
        pv[cf] = pvec[cf * 16 + r];
        bb[cf] = brel[cf * 16 + r];
        q += pv[cf] * pv[cf];
    }
    float dots[4] = {0.f, 0.f, 0.f, 0.f};
#pragma unroll
    for (int cf = 0; cf < 8; cf++) {
#pragma unroll
        for (int reg = 0; reg < 4; reg++) {
            float v = acc[cf][reg] + bb[cf];
            v = v > 0.f ? v : 0.f;
            hout[(size_t)(rows0 + kb * 4 + reg) * CCH + cf * 16 + r] = pksplit(v);
            dots[reg] += v * pv[cf];
        }
    }
#pragma unroll
    for (int off = 1; off < 16; off <<= 1) {
        q += __shfl_xor(q, off);
#pragma unroll
        for (int reg = 0; reg < 4; reg++) dots[reg] += __shfl_xor(dots[reg], off);
    }
    if (r == 0) {
        float inv_norm = rsqrtf(q);
#pragma unroll
        for (int reg = 0; reg < 4; reg++)
            score[rows0 + kb * 4 + reg] = tanhf(dots[reg] * inv_norm);
    }
}

// ---------------- fused pool with RADIX-SELECT (no sort):
//   stage slab (node order), select top-k set via radix on u64 keys,
//   rank = node-order prefix of selection mask, scale, readout,
//   materialize pooledX, edge-agg, next CSR (q==0) ----------------
__global__ __launch_bounds__(1024) void pool_kernel(
        const float* __restrict__ score, const uint* __restrict__ hp,
        float* __restrict__ gpart,           // this layer's [B_G][256] slice
        const int* __restrict__ ipt_in, const int* __restrict__ cnt_in,
        const ushort* __restrict__ src_in,
        int* __restrict__ ipt_out, int* __restrict__ cnt_out,
        ushort* __restrict__ src_out,
        uint* __restrict__ pooledX, uint* __restrict__ aggout,
        int n, int k, int do_next) {
    int b = blockIdx.x >> 2, q = blockIdx.x & 3;
    int tid = threadIdx.x;
    __shared__ short invl[512];          // node -> rank / -1
    __shared__ short old_of[512];        // rank -> node
    __shared__ float sval[512];          // node -> score value
    __shared__ int hist[256];
    __shared__ int cum[257];
    __shared__ int bc[1];
    __shared__ float redbuf[1024];       // 4 KB: 16 workers x 32 ch x {max,sum}
    __shared__ int prefL[512];
    __shared__ int wtot[8], woff[8];
    extern __shared__ float slab[];      // [n][32] fp32, column-swizzled, node order

    // 1. stage slab (all 1024 threads, sequential plane read) + build keys
    u64 key = 0ull;
    bool has = (tid < n);
    if (has) {
        uint u = __float_as_uint(score[b * n + tid]);
        u = (u & 0x80000000u) ? ~u : (u | 0x80000000u);
        key = ((u64)u << 32) | (uint)(~tid);
        sval[tid] = keyval(key);
    }
    for (int t = tid; t < n * 8; t += 1024) {
        int nd = t >> 3, c4 = t & 7;
        uint4 u = *(const uint4*)&hp[(size_t)(b * n + nd) * CCH + q * 32 + c4 * 4];
        *(float4*)&slab[nd * 32 + SWZ(nd, c4)] =
            make_float4(unpk(u.x), unpk(u.y), unpk(u.z), unpk(u.w));
    }
    // 2. radix select: find top-k set by descending key
    bool active = has, sure = false;
    int rem = k;
    for (int pass = 0; pass < 8; pass++) {
        int dig = (int)((key >> (56 - 8 * pass)) & 255);
        if (tid < 256) hist[tid] = 0;
        __syncthreads();
        if (active) atomicAdd(&hist[dig], 1);
        __syncthreads();
        if (tid < 64) {
            int b0 = hist[tid * 4], b1 = hist[tid * 4 + 1];
            int b2 = hist[tid * 4 + 2], b3 = hist[tid * 4 + 3];
            int s = b0 + b1 + b2 + b3;
            int suf = s;
#pragma unroll
            for (int o = 1; o < 64; o <<= 1) {
                int t2 = __shfl_down(suf, o);
                if (tid + o < 64) suf += t2;
            }
            int after = suf - s;      // sum over lanes > tid
            cum[tid * 4 + 3] = after + b3;
            cum[tid * 4 + 2] = after + b3 + b2;
            cum[tid * 4 + 1] = after + b3 + b2 + b1;
            cum[tid * 4 + 0] = after + s;
            if (tid == 0) cum[256] = 0;
        }
        __syncthreads();
        if (tid < 256 && cum[tid] >= rem && cum[tid + 1] < rem) bc[0] = tid;
        __syncthreads();
        int dstar = bc[0];
        int hcnt = hist[dstar];
        rem -= cum[dstar + 1];
        if (active) {
            if (dig > dstar) { sure = true; active = false; }
            else if (dig < dstar) active = false;
        }
        __syncthreads();
        if (hcnt == 1) break;
    }
    bool sel = sure || (active && rem > 0);
    // 3. rank = node-order exclusive prefix of sel
    {
        int lane = tid & 63;
        int v = sel ? 1 : 0;
        int incl = v;
#pragma unroll
        for (int o = 1; o < 64; o <<= 1) {
            int t2 = __shfl_up(incl, o);
            if (lane >= o) incl += t2;
        }
        if (tid < 512 && lane == 63) wtot[tid >> 6] = incl;
        __syncthreads();
        if (tid < 8) {
            int s = 0;
            for (int w = 0; w < tid; w++) s += wtot[w];
            woff[tid] = s;
        }
        __syncthreads();
        if (tid < 512) {
            int rank = incl - v + woff[tid >> 6];
            invl[tid] = sel ? (short)rank : (short)-1;
            if (sel) old_of[rank] = (short)tid;
        }
        __syncthreads();
    }
    // 4. scale selected rows in-place (node order, independent addresses)
    for (int t = tid; t < n * 8; t += 1024) {
        int nd = t >> 3, c4 = t & 7;
        if (invl[nd] >= 0) {
            float v = sval[nd];
            float* p = &slab[nd * 32 + SWZ(nd, c4)];
            p[0] *= v; p[1] *= v; p[2] *= v; p[3] *= v;
        }
    }
    __syncthreads();
    // 5. readout: node order, 16 workers x 32 channels
    if (tid < 512) {
        int w = tid >> 5, ch = tid & 31;
        int cb = ch >> 2, ce = ch & 3;
        float mx = -1e30f, sm = 0.f;
        for (int nd = w; nd < n; nd += 16) {
            float v = slab[nd * 32 + SWZ(nd, cb) + ce];
            if (invl[nd] >= 0) { mx = fmaxf(mx, v); sm += v; }
        }
        redbuf[w * 32 + ch] = mx;
        redbuf[512 + w * 32 + ch] = sm;
    }
    __syncthreads();
    if (tid < 32) {
        float m = -1e30f, s = 0.f;
        for (int w = 0; w < 16; w++) {
            m = fmaxf(m, redbuf[w * 32 + tid]);
            s += redbuf[512 + w * 32 + tid];
        }
        gpart[b * 256 + q * 32 + tid] = m;
        gpart[b * 256 + 128 + q * 32 + tid] = s / (float)k;
    }
    if (!do_next) return;
    // 6. materialize pooledX (rank-major, sequential write)
    for (int t = tid; t < k * 8; t += 1024) {
        int rank = t >> 3, c4 = t & 7;
        int old = (int)old_of[rank];
        const float* p = &slab[old * 32 + SWZ(old, c4)];
        uint4 o;
        o.x = pksplit(p[0]); o.y = pksplit(p[1]);
        o.z = pksplit(p[2]); o.w = pksplit(p[3]);
        *(uint4*)&pooledX[(size_t)(b * k + rank) * CCH + q * 32 + c4 * 4] = o;
    }
    // 7. edge-aggregate: rank d sums scaled slab rows of selected in-neighbors
    {
        int wave = tid >> 6, lane = tid & 63;
        int gl = lane >> 3, sub = lane & 7;
        int ngroups = (k + 7) >> 3;
        for (int g = wave; g < ngroups; g += 16) {
            int d = g * 8 + gl;
            bool act = d < k;
            int beg = 0, cc = 0;
            if (act) {
                int old = (int)old_of[d];
                beg = ipt_in[b * n + old];
                cc = cnt_in[b * n + old];
            }
            float4 acc = make_float4(0.f, 0.f, 0.f, 0.f);
            int s_next = (cc > 0) ? (int)src_in[beg] : 0;
            for (int j = 0; j < cc; j++) {
                int s = s_next;
                if (j + 1 < cc) s_next = (int)src_in[beg + j + 1];
                if (invl[s] >= 0) {
                    const float4 v = *(const float4*)&slab[s * 32 + SWZ(s, sub)];
                    acc.x += v.x; acc.y += v.y; acc.z += v.z; acc.w += v.w;
                }
            }
            if (act) {
                uint4 o;
                o.x = pksplit(acc.x); o.y = pksplit(acc.y);
                o.z = pksplit(acc.z); o.w = pksplit(acc.w);
                *(uint4*)&aggout[(size_t)(b * k + d) * CCH + q * 32 + sub * 4] = o;
            }
        }
    }
    // 8. q==0: build next-layer CSR (new ids = ranks)
    if (q == 0) {
        int beg = 0, c = 0, nk = 0;
        if (tid < k) {
            int old = (int)old_of[tid];
            beg = ipt_in[b * n + old];
            c = cnt_in[b * n + old];
            for (int t = 0; t < c; t++)
                if (invl[src_in[beg + t]] >= 0) nk++;
        }
        int lane = tid & 63;
        int incl = (tid < 512 && tid < k) ? nk : 0;
#pragma unroll
        for (int o = 1; o < 64; o <<= 1) {
            int t2 = __shfl_up(incl, o);
            if (lane >= o) incl += t2;
        }
        if (tid < 512 && lane == 63) wtot[tid >> 6] = incl;
        __syncthreads();
        if (tid < 8) {
            int s = 0;
            for (int w = 0; w < tid; w++) s += wtot[w];
            woff[tid] = s;
        }
        __syncthreads();
        if (tid < 512) prefL[tid] = incl + woff[tid >> 6];
        __syncthreads();
        if (tid < k) {
            int excl = tid ? prefL[tid - 1] : 0;
            ipt_out[b * k + tid] = b * EPG + excl;
            cnt_out[b * k + tid] = nk;
            int pos = b * EPG + excl;
            for (int t = 0; t < c; t++) {
                int ns = invl[src_in[beg + t]];
                if (ns >= 0) src_out[pos++] = (ushort)ns;
            }
        }
    }
}

// ---------------- final MLP + log_softmax ----------------
__global__ __launch_bounds__(128) void mlp_kernel(const float* __restrict__ gpart,
        const float* __restrict__ W1, const float* __restrict__ b1,
        const float* __restrict__ W2, const float* __restrict__ b2,
        const float* __restrict__ W3, const float* __restrict__ b3,
        float* __restrict__ out) {
    int b = blockIdx.x, t = threadIdx.x;
    __shared__ float gs[256], h1[128], h2[64], lg[10];
    const float* g0 = gpart + ((size_t)0 * B_G + b) * 256;
    const float* g1 = gpart + ((size_t)1 * B_G + b) * 256;
    const float* g2 = gpart + ((size_t)2 * B_G + b) * 256;
    gs[t] = g0[t] + g1[t] + g2[t];
    gs[128 + t] = g0[128 + t] + g1[128 + t] + g2[128 + t];
    __syncthreads();
    {
        float a = b1[t];
        for (int c = 0; c < 256; c++) a += gs[c] * W1[c * 128 + t];
        h1[t] = fmaxf(a, 0.f);
    }
    __syncthreads();
    if (t < 64) {
        float a = b2[t];
        for (int c = 0; c < 128; c++) a += h1[c] * W2[c * 64 + t];
        h2[t] = fmaxf(a, 0.f);
    }
    __syncthreads();
    if (t < 10) {
        float a = b3[t];
        for (int c = 0; c < 64; c++) a += h2[c] * W3[c * 10 + t];
        lg[t] = a;
    }
    __syncthreads();
    if (t < 10) {
        float m = lg[0];
        for (int i = 1; i < 10; i++) m = fmaxf(m, lg[i]);
        float s = 0.f;
        for (int i = 0; i < 10; i++) s += expf(lg[i] - m);
        out[b * 10 + t] = lg[t] - m - logf(s);
    }
}

// ---------------- host ----------------
extern "C" void kernel_launch(void* const* d_in, const int* in_sizes, int n_in,
                              void* d_out, int out_size, void* d_ws, size_t ws_size,
                              hipStream_t stream) {
    (void)in_sizes; (void)n_in; (void)out_size; (void)ws_size;
    const float* x0 = (const float*)d_in[0];
    const int* es = (const int*)d_in[1];
    const int* ed = (const int*)d_in[2];
    const float* Wroot[3] = {(const float*)d_in[3], (const float*)d_in[7], (const float*)d_in[11]};
    const float* Wrel[3]  = {(const float*)d_in[4], (const float*)d_in[8], (const float*)d_in[12]};
    const float* brel[3]  = {(const float*)d_in[5], (const float*)d_in[9], (const float*)d_in[13]};
    const float* pvec[3]  = {(const float*)d_in[6], (const float*)d_in[10], (const float*)d_in[14]};
    const float* W1 = (const float*)d_in[15];
    const float* b1 = (const float*)d_in[16];
    const float* W2 = (const float*)d_in[17];
    const float* b2 = (const float*)d_in[18];
    const float* W3 = (const float*)d_in[19];
    const float* b3 = (const float*)d_in[20];

    size_t off = 0;
    char* base = (char*)d_ws;
    auto alloc = [&](size_t bytes) -> void* {
        void* p = base + off;
        off += (bytes + 255) & ~(size_t)255;
        return p;
    };
    const size_t FEATP = (size_t)(B_G * N0) * CCH * 4;   // packed uint plane
    uint* P0 = (uint*)alloc(FEATP);
    uint* P1 = (uint*)alloc(FEATP);
    uint* P2 = (uint*)alloc(FEATP);
    ushort* Bph = (ushort*)alloc((size_t)3 * 32768 * 2);
    ushort* Bpl = (ushort*)alloc((size_t)3 * 32768 * 2);
    int* iptA = (int*)alloc((size_t)(B_G * N0) * 4);
    int* cntA = (int*)alloc((size_t)(B_G * N0) * 4);
    ushort* srcA = (ushort*)alloc((size_t)E_TOTAL * 2);
    int* iptB = (int*)alloc((size_t)(B_G * N0) * 4);
    int* cntB = (int*)alloc((size_t)(B_G * N0) * 4);
    ushort* srcB = (ushort*)alloc((size_t)E_TOTAL * 2);
    float* score = (float*)alloc((size_t)(B_G * N0) * 4);
    float* gpart = (float*)alloc((size_t)3 * B_G * 256 * 4);

    setup_kernel<<<B_G + (3 * 32768 + 511) / 512, 512, 0, stream>>>(
        Wrel[0], Wroot[0], Wrel[1], Wroot[1], Wrel[2], Wroot[2],
        Bph, Bpl, es, ed, iptA, cntA, srcA);

    // L0
    aggregate0<<<4 * B_G, 1024, (size_t)N0 * 32 * 4, stream>>>(
        x0, iptA, cntA, srcA, P1);
    transform_mfma<<<B_G * N0 / 128, 512, 0, stream>>>(
        P1, nullptr, x0, Bph, Bpl, brel[0], pvec[0], P0, score);
    pool_kernel<<<4 * B_G, 1024, (size_t)N0 * 32 * 4, stream>>>(
        score, P0, gpart + (size_t)0 * B_G * 256,
        iptA, cntA, srcA, iptB, cntB, srcB, P2, P1, N0, K1, 1);

    // L1
    transform_mfma<<<B_G * K1 / 128, 512, 0, stream>>>(
        P1, P2, nullptr, Bph + 32768, Bpl + 32768, brel[1], pvec[1], P0, score);
    pool_kernel<<<4 * B_G, 1024, (size_t)K1 * 32 * 4, stream>>>(
        score, P0, gpart + (size_t)1 * B_G * 256,
        iptB, cntB, srcB, iptA, cntA, srcA, P2, P1, K1, K2, 1);

    // L2
    transform_mfma<<<B_G * K2 / 128, 512, 0, stream>>>(
        P1, P2, nullptr, Bph + 2 * 32768, Bpl + 2 * 32768, brel[2], pvec[2], P0, score);
    pool_kernel<<<4 * B_G, 1024, (size_t)K2 * 32 * 4, stream>>>(
        score, P0, gpart + (size_t)2 * B_G * 256,
        iptA, cntA, srcA, nullptr, nullptr, nullptr, nullptr, nullptr, K2, K3, 0);

    mlp_kernel<<<B_G, 128, 0, stream>>>(gpart, W1, b1, W2, b2, W3, b3, (float*)d_out);
}

// Round 21
// 193.764 us; speedup vs baseline: 1.0300x; 1.0300x over previous
//
#include <hip/hip_runtime.h>
#include <hip/hip_bf16.h>
#include <math.h>

#define B_G   128
#define N0    512
#define DEG   8
#define CCH   128
#define EPG   (N0*DEG)            // 4096 edges per graph (fixed slab)
#define E_TOTAL (B_G*EPG)
#define K1    410
#define K2    328
#define K3    263
#define NCLS  10

// swizzled float4-block offset within a 32-float row: kills 8-way bank conflicts
#define SWZ(row, cb) ((((cb) ^ ((row) & 7)) << 2))

using bf16x8 = __attribute__((ext_vector_type(8))) __bf16;
using f32x4  = __attribute__((ext_vector_type(4))) float;
typedef unsigned short ushort;
typedef unsigned int uint;
typedef unsigned long long u64;

__device__ __forceinline__ ushort f2b(float f) {
    uint u = __float_as_uint(f);
    u += 0x7fffu + ((u >> 16) & 1u);      // RNE
    return (ushort)(u >> 16);
}
__device__ __forceinline__ float b2f(ushort h) {
    return __uint_as_float(((uint)h) << 16);
}
__device__ __forceinline__ void split2(float v, ushort& hi, ushort& lo) {
    hi = f2b(v);
    lo = f2b(v - b2f(hi));
}
__device__ __forceinline__ uint pksplit(float v) {
    ushort h, l; split2(v, h, l);
    return (uint)h | ((uint)l << 16);
}
__device__ __forceinline__ float unpk(uint u) {
    return __uint_as_float(u << 16) + __uint_as_float(u & 0xffff0000u);
}
__device__ __forceinline__ float keyval(u64 key) {
    uint tu = (uint)(key >> 32);
    uint su = (tu & 0x80000000u) ? (tu & 0x7fffffffu) : ~tu;
    return __uint_as_float(su);
}

// ---------------- setup: static CSR (blocks 0..B_G-1) | pack weights ----------------
__global__ __launch_bounds__(512) void setup_kernel(
        const float* __restrict__ Wrel0, const float* __restrict__ Wroot0,
        const float* __restrict__ Wrel1, const float* __restrict__ Wroot1,
        const float* __restrict__ Wrel2, const float* __restrict__ Wroot2,
        ushort* __restrict__ Bph, ushort* __restrict__ Bpl,
        const int* __restrict__ es, const int* __restrict__ ed,
        int* __restrict__ indptr0, int* __restrict__ counts0, ushort* __restrict__ srclist0) {
    __shared__ uint epk[EPG];     // 16 KB
    __shared__ int cnt[512], pref[512], curs[512];
    if (blockIdx.x < B_G) {
        int b = blockIdx.x, tid = threadIdx.x;
        cnt[tid] = 0;
        __syncthreads();
        int base = b * EPG;
        for (int i = tid; i < EPG; i += 512) {
            int s = es[base + i] & (N0 - 1);
            int d = ed[base + i] & (N0 - 1);
            epk[i] = (uint)s | ((uint)d << 16);
            atomicAdd(&cnt[d], 1);
        }
        __syncthreads();
        pref[tid] = cnt[tid];
        __syncthreads();
        for (int off = 1; off < 512; off <<= 1) {
            int v = (tid >= off) ? pref[tid - off] : 0;
            __syncthreads();
            pref[tid] += v;
            __syncthreads();
        }
        int excl = tid ? pref[tid - 1] : 0;
        indptr0[b * N0 + tid] = base + excl;
        counts0[b * N0 + tid] = cnt[tid];
        curs[tid] = excl;
        __syncthreads();
        for (int i = tid; i < EPG; i += 512) {
            uint wv = epk[i];
            int dl = wv >> 16;
            int pos = atomicAdd(&curs[dl], 1);
            srclist0[base + pos] = (ushort)(wv & 0xFFFFu);
        }
    } else {
        int i = (blockIdx.x - B_G) * 512 + threadIdx.x;
        if (i < 3 * 32768) {
            int layer = i >> 15, rem = i & 32767;
            int j = rem & 7, lane = (rem >> 3) & 63, cf = (rem >> 9) & 7, ks = rem >> 12;
            int k = ks * 32 + (lane >> 4) * 8 + j;
            int c = cf * 16 + (lane & 15);
            const float* Wrel  = layer == 0 ? Wrel0  : layer == 1 ? Wrel1  : Wrel2;
            const float* Wroot = layer == 0 ? Wroot0 : layer == 1 ? Wroot1 : Wroot2;
            float v = (k < 128) ? Wrel[k * 128 + c] : Wroot[(k - 128) * 128 + c];
            ushort hi, lo; split2(v, hi, lo);
            Bph[i] = hi; Bpl[i] = lo;
        }
    }
}

// ---------------- layer-0 aggregation: fp32 x0 direct, swizzled LDS slab ----------------
__global__ __launch_bounds__(1024) void aggregate0(
        const float* __restrict__ xf,
        const int* __restrict__ indptr, const int* __restrict__ counts,
        const ushort* __restrict__ srclist,
        uint* __restrict__ aggp) {
    extern __shared__ float slab[];            // [512][32] fp32, column-swizzled
    int b = blockIdx.x >> 2, q = blockIdx.x & 3;
    int tid = threadIdx.x;
    const float4* xf4 = (const float4*)xf;     // row = 32 float4s
    for (int t = tid; t < N0 * 8; t += 1024) {
        int nd = t >> 3, c4 = t & 7;
        float4 u = xf4[(size_t)(b * N0 + nd) * 32 + q * 8 + c4];
        *(float4*)&slab[nd * 32 + SWZ(nd, c4)] = u;
    }
    __syncthreads();
    int wave = tid >> 6, lane = tid & 63;
    int gl = lane >> 3, sub = lane & 7;
    for (int g = wave; g < N0 / 8; g += 16) {
        int d = g * 8 + gl;
        int beg = indptr[b * N0 + d];
        int cnt = counts[b * N0 + d];
        float4 acc = make_float4(0.f, 0.f, 0.f, 0.f);
        int id_next = (cnt > 0) ? (int)srclist[beg] : 0;
        for (int j = 0; j < cnt; j++) {
            int id = id_next;
            if (j + 1 < cnt) id_next = (int)srclist[beg + j + 1];
            const float4 v = *(const float4*)&slab[id * 32 + SWZ(id, sub)];
            acc.x += v.x; acc.y += v.y; acc.z += v.z; acc.w += v.w;
        }
        uint4 o;
        o.x = pksplit(acc.x); o.y = pksplit(acc.y);
        o.z = pksplit(acc.z); o.w = pksplit(acc.w);
        *(uint4*)&aggp[(size_t)(b * N0 + d) * CCH + q * 32 + sub * 4] = o;
    }
}

// ---------------- bf16x3 MFMA transform + fused score (LDS-staged B) ----------------
// Always processes all B_G*N0 row slots (dead rows produce garbage, masked later).
__global__ __launch_bounds__(512, 4) void transform_mfma(
        const uint* __restrict__ aggp, const uint* __restrict__ rootp,
        const float* __restrict__ rootf,
        const ushort* __restrict__ Bph, const ushort* __restrict__ Bpl,
        const float* __restrict__ brel, const float* __restrict__ pvec,
        uint* __restrict__ hout, float* __restrict__ score) {
    __shared__ ushort ldsBh[16384];   // 32 KB: [4 ks][8 cf][64 lane][8]
    __shared__ ushort ldsBl[16384];   // 32 KB
    int tid = threadIdx.x;
    int wave = tid >> 6, lane = tid & 63;
    int r = lane & 15, kb = lane >> 4;
    int rows0 = blockIdx.x * 128 + wave * 16;
    int gid = rows0 + r;

    f32x4 acc[8];
#pragma unroll
    for (int cf = 0; cf < 8; cf++) acc[cf] = (f32x4)(0.f);

    union U16 { uint u[4]; bf16x8 v; };

#pragma unroll
    for (int half = 0; half < 2; half++) {
        if (half) __syncthreads();
#pragma unroll
        for (int i = 0; i < 4; i++) {
            int idx = tid + i * 512;
            ((uint4*)ldsBh)[idx] = ((const uint4*)(Bph + half * 16384))[idx];
            ((uint4*)ldsBl)[idx] = ((const uint4*)(Bpl + half * 16384))[idx];
        }
        __syncthreads();
#pragma unroll
        for (int ks4 = 0; ks4 < 4; ks4++) {
            U16 ah, al;
            if (half && rootf) {
                const float* R = rootf + (size_t)gid * CCH + ks4 * 32 + kb * 8;
                float4 f0 = *(const float4*)R;
                float4 f1 = *(const float4*)(R + 4);
                float c[8] = {f0.x, f0.y, f0.z, f0.w, f1.x, f1.y, f1.z, f1.w};
#pragma unroll
                for (int p2 = 0; p2 < 4; p2++) {
                    ushort h0, l0, h1, l1;
                    split2(c[2 * p2], h0, l0);
                    split2(c[2 * p2 + 1], h1, l1);
                    ah.u[p2] = (uint)h0 | ((uint)h1 << 16);
                    al.u[p2] = (uint)l0 | ((uint)l1 << 16);
                }
            } else {
                const uint* A = half ? rootp : aggp;
                size_t rowbase = (size_t)gid * CCH + ks4 * 32 + kb * 8;
                uint4 ua = *(const uint4*)&A[rowbase];
                uint4 ub = *(const uint4*)&A[rowbase + 4];
                ah.u[0] = (ua.x & 0xffffu) | (ua.y << 16);
                ah.u[1] = (ua.z & 0xffffu) | (ua.w << 16);
                ah.u[2] = (ub.x & 0xffffu) | (ub.y << 16);
                ah.u[3] = (ub.z & 0xffffu) | (ub.w << 16);
                al.u[0] = (ua.x >> 16) | (ua.y & 0xffff0000u);
                al.u[1] = (ua.z >> 16) | (ua.w & 0xffff0000u);
                al.u[2] = (ub.x >> 16) | (ub.y & 0xffff0000u);
                al.u[3] = (ub.z >> 16) | (ub.w & 0xffff0000u);
            }
#pragma unroll
            for (int cf = 0; cf < 8; cf++) {
                bf16x8 bh = *(const bf16x8*)&ldsBh[((ks4 * 8 + cf) * 64 + lane) * 8];
                bf16x8 bl = *(const bf16x8*)&ldsBl[((ks4 * 8 + cf) * 64 + lane) * 8];
                acc[cf] = __builtin_amdgcn_mfma_f32_16x16x32_bf16(ah.v, bl, acc[cf], 0, 0, 0);
                acc[cf] = __builtin_amdgcn_mfma_f32_16x16x32_bf16(al.v, bh, acc[cf], 0, 0, 0);
                acc[cf] = __builtin_amdgcn_mfma_f32_16x16x32_bf16(ah.v, bh, acc[cf], 0, 0, 0);
            }
        }
    }

    float pv[8], bb[8], q = 0.f;
#pragma unroll
    for (int cf = 0; cf < 8; cf++) {
        pv[cf] = pvec[cf * 16 + r];
        bb[cf] = brel[cf * 16 + r];
        q += pv[cf] * pv[cf];
    }
    float dots[4] = {0.f, 0.f, 0.f, 0.f};
#pragma unroll
    for (int cf = 0; cf < 8; cf++) {
#pragma unroll
        for (int reg = 0; reg < 4; reg++) {
            float v = acc[cf][reg] + bb[cf];
            v = v > 0.f ? v : 0.f;
            hout[(size_t)(rows0 + kb * 4 + reg) * CCH + cf * 16 + r] = pksplit(v);
            dots[reg] += v * pv[cf];
        }
    }
#pragma unroll
    for (int off = 1; off < 16; off <<= 1) {
        q += __shfl_xor(q, off);
#pragma unroll
        for (int reg = 0; reg < 4; reg++) dots[reg] += __shfl_xor(dots[reg], off);
    }
    if (r == 0) {
        float inv_norm = rsqrtf(q);
#pragma unroll
        for (int reg = 0; reg < 4; reg++)
            score[rows0 + kb * 4 + reg] = tanhf(dots[reg] * inv_norm);
    }
}

// ---------------- pool (no renumbering): radix-select sets validity mask,
//   in-place scale of h plane, masked readout, masked edge-agg over STATIC CSR ----------------
__global__ __launch_bounds__(1024) void pool_kernel(
        const float* __restrict__ score, uint* __restrict__ hp,
        float* __restrict__ gpart,            // this layer's [B_G][256] slice
        const int* __restrict__ ipt, const int* __restrict__ cnt,
        const ushort* __restrict__ srcl,      // static CSR
        const int* __restrict__ valid_in,     // null = all valid (layer 0)
        int* __restrict__ valid_out,          // null on last layer
        uint* __restrict__ aggout,            // null on last layer
        int k) {
    int b = blockIdx.x >> 2, q = blockIdx.x & 3;
    int tid = threadIdx.x;
    __shared__ char selm[512];
    __shared__ float sval[512];
    __shared__ int hist[256];
    __shared__ int cum[257];
    __shared__ int bc[1];
    __shared__ float redbuf[2048];            // 8 KB: 32 workers x 32 ch x {max,sum}
    extern __shared__ float slab[];           // [512][32] fp32, column-swizzled

    // 1. keys (masked by validity) + stage slab (node order, sequential)
    u64 key = 0ull;
    if (tid < 512) {
        bool v = (!valid_in) || (valid_in[b * N0 + tid] != 0);
        if (v) {
            uint u = __float_as_uint(score[b * N0 + tid]);
            u = (u & 0x80000000u) ? ~u : (u | 0x80000000u);
            key = ((u64)u << 32) | (uint)(~tid);
            sval[tid] = keyval(key);
        }
    }
    for (int t = tid; t < N0 * 8; t += 1024) {
        int nd = t >> 3, c4 = t & 7;
        uint4 u = *(const uint4*)&hp[(size_t)(b * N0 + nd) * CCH + q * 32 + c4 * 4];
        *(float4*)&slab[nd * 32 + SWZ(nd, c4)] =
            make_float4(unpk(u.x), unpk(u.y), unpk(u.z), unpk(u.w));
    }
    // 2. radix select top-k among valid keys (key==0 excluded)
    bool active = (tid < 512) && (key != 0ull), sure = false;
    int rem = k;
    for (int pass = 0; pass < 8; pass++) {
        int dig = (int)((key >> (56 - 8 * pass)) & 255);
        if (tid < 256) hist[tid] = 0;
        __syncthreads();
        if (active) atomicAdd(&hist[dig], 1);
        __syncthreads();
        if (tid < 64) {
            int b0 = hist[tid * 4], b1 = hist[tid * 4 + 1];
            int b2 = hist[tid * 4 + 2], b3 = hist[tid * 4 + 3];
            int s = b0 + b1 + b2 + b3;
            int suf = s;
#pragma unroll
            for (int o = 1; o < 64; o <<= 1) {
                int t2 = __shfl_down(suf, o);
                if (tid + o < 64) suf += t2;
            }
            int after = suf - s;      // sum over lanes > tid
            cum[tid * 4 + 3] = after + b3;
            cum[tid * 4 + 2] = after + b3 + b2;
            cum[tid * 4 + 1] = after + b3 + b2 + b1;
            cum[tid * 4 + 0] = after + s;
            if (tid == 0) cum[256] = 0;
        }
        __syncthreads();
        if (tid < 256 && cum[tid] >= rem && cum[tid + 1] < rem) bc[0] = tid;
        __syncthreads();
        int dstar = bc[0];
        int hcnt = hist[dstar];
        rem -= cum[dstar + 1];
        if (active) {
            if (dig > dstar) { sure = true; active = false; }
            else if (dig < dstar) active = false;
        }
        __syncthreads();
        if (hcnt == 1) break;
    }
    bool sel = sure || (active && rem > 0);
    if (tid < 512) selm[tid] = sel ? 1 : 0;
    __syncthreads();
    // 3. scale selected rows in slab; write scaled rows back to hp (in-place)
    for (int t = tid; t < N0 * 8; t += 1024) {
        int nd = t >> 3, c4 = t & 7;
        if (selm[nd]) {
            float v = sval[nd];
            float* p = &slab[nd * 32 + SWZ(nd, c4)];
            float a0 = p[0] * v, a1 = p[1] * v, a2 = p[2] * v, a3 = p[3] * v;
            p[0] = a0; p[1] = a1; p[2] = a2; p[3] = a3;
            if (valid_out) {
                uint4 o;
                o.x = pksplit(a0); o.y = pksplit(a1);
                o.z = pksplit(a2); o.w = pksplit(a3);
                *(uint4*)&hp[(size_t)(b * N0 + nd) * CCH + q * 32 + c4 * 4] = o;
            }
        }
    }
    __syncthreads();
    // 4. masked readout: 32 workers x 32 channels, node order
    {
        int w = tid >> 5, ch = tid & 31;
        int cb = ch >> 2, ce = ch & 3;
        float mx = -1e30f, sm = 0.f;
        for (int nd = w; nd < N0; nd += 32) {
            float v = slab[nd * 32 + SWZ(nd, cb) + ce];
            if (selm[nd]) { mx = fmaxf(mx, v); sm += v; }
        }
        redbuf[w * 32 + ch] = mx;
        redbuf[1024 + w * 32 + ch] = sm;
    }
    __syncthreads();
    if (tid < 32) {
        float m = -1e30f, s = 0.f;
        for (int w = 0; w < 32; w++) {
            m = fmaxf(m, redbuf[w * 32 + tid]);
            s += redbuf[1024 + w * 32 + tid];
        }
        gpart[b * 256 + q * 32 + tid] = m;
        gpart[b * 256 + 128 + q * 32 + tid] = s / (float)k;
    }
    if (!valid_out) return;
    // 5. q==0 publishes new validity mask
    if (q == 0 && tid < 512) valid_out[b * N0 + tid] = selm[tid] ? 1 : 0;
    // 6. masked edge-aggregate over STATIC CSR (src & dst gated by new mask)
    {
        int wave = tid >> 6, lane = tid & 63;
        int gl = lane >> 3, sub = lane & 7;
        for (int g = wave; g < N0 / 8; g += 16) {
            int d = g * 8 + gl;
            bool act = selm[d] != 0;
            int beg = 0, cc = 0;
            if (act) { beg = ipt[b * N0 + d]; cc = cnt[b * N0 + d]; }
            float4 acc = make_float4(0.f, 0.f, 0.f, 0.f);
            int s_next = (cc > 0) ? (int)srcl[beg] : 0;
            for (int j = 0; j < cc; j++) {
                int s = s_next;
                if (j + 1 < cc) s_next = (int)srcl[beg + j + 1];
                if (selm[s]) {
                    const float4 v = *(const float4*)&slab[s * 32 + SWZ(s, sub)];
                    acc.x += v.x; acc.y += v.y; acc.z += v.z; acc.w += v.w;
                }
            }
            if (act) {
                uint4 o;
                o.x = pksplit(acc.x); o.y = pksplit(acc.y);
                o.z = pksplit(acc.z); o.w = pksplit(acc.w);
                *(uint4*)&aggout[(size_t)(b * N0 + d) * CCH + q * 32 + sub * 4] = o;
            }
        }
    }
}

// ---------------- final MLP + log_softmax ----------------
__global__ __launch_bounds__(128) void mlp_kernel(const float* __restrict__ gpart,
        const float* __restrict__ W1, const float* __restrict__ b1,
        const float* __restrict__ W2, const float* __restrict__ b2,
        const float* __restrict__ W3, const float* __restrict__ b3,
        float* __restrict__ out) {
    int b = blockIdx.x, t = threadIdx.x;
    __shared__ float gs[256], h1[128], h2[64], lg[10];
    const float* g0 = gpart + ((size_t)0 * B_G + b) * 256;
    const float* g1 = gpart + ((size_t)1 * B_G + b) * 256;
    const float* g2 = gpart + ((size_t)2 * B_G + b) * 256;
    gs[t] = g0[t] + g1[t] + g2[t];
    gs[128 + t] = g0[128 + t] + g1[128 + t] + g2[128 + t];
    __syncthreads();
    {
        float a = b1[t];
        for (int c = 0; c < 256; c++) a += gs[c] * W1[c * 128 + t];
        h1[t] = fmaxf(a, 0.f);
    }
    __syncthreads();
    if (t < 64) {
        float a = b2[t];
        for (int c = 0; c < 128; c++) a += h1[c] * W2[c * 64 + t];
        h2[t] = fmaxf(a, 0.f);
    }
    __syncthreads();
    if (t < 10) {
        float a = b3[t];
        for (int c = 0; c < 64; c++) a += h2[c] * W3[c * 10 + t];
        lg[t] = a;
    }
    __syncthreads();
    if (t < 10) {
        float m = lg[0];
        for (int i = 1; i < 10; i++) m = fmaxf(m, lg[i]);
        float s = 0.f;
        for (int i = 0; i < 10; i++) s += expf(lg[i] - m);
        out[b * 10 + t] = lg[t] - m - logf(s);
    }
}

// ---------------- host ----------------
extern "C" void kernel_launch(void* const* d_in, const int* in_sizes, int n_in,
                              void* d_out, int out_size, void* d_ws, size_t ws_size,
                              hipStream_t stream) {
    (void)in_sizes; (void)n_in; (void)out_size; (void)ws_size;
    const float* x0 = (const float*)d_in[0];
    const int* es = (const int*)d_in[1];
    const int* ed = (const int*)d_in[2];
    const float* Wroot[3] = {(const float*)d_in[3], (const float*)d_in[7], (const float*)d_in[11]};
    const float* Wrel[3]  = {(const float*)d_in[4], (const float*)d_in[8], (const float*)d_in[12]};
    const float* brel[3]  = {(const float*)d_in[5], (const float*)d_in[9], (const float*)d_in[13]};
    const float* pvec[3]  = {(const float*)d_in[6], (const float*)d_in[10], (const float*)d_in[14]};
    const float* W1 = (const float*)d_in[15];
    const float* b1 = (const float*)d_in[16];
    const float* W2 = (const float*)d_in[17];
    const float* b2 = (const float*)d_in[18];
    const float* W3 = (const float*)d_in[19];
    const float* b3 = (const float*)d_in[20];

    size_t off = 0;
    char* base = (char*)d_ws;
    auto alloc = [&](size_t bytes) -> void* {
        void* p = base + off;
        off += (bytes + 255) & ~(size_t)255;
        return p;
    };
    const size_t FEATP = (size_t)(B_G * N0) * CCH * 4;   // packed uint plane
    uint* PA = (uint*)alloc(FEATP);          // h plane A
    uint* PB = (uint*)alloc(FEATP);          // h plane B
    uint* P1 = (uint*)alloc(FEATP);          // agg plane
    ushort* Bph = (ushort*)alloc((size_t)3 * 32768 * 2);
    ushort* Bpl = (ushort*)alloc((size_t)3 * 32768 * 2);
    int* ipt = (int*)alloc((size_t)(B_G * N0) * 4);
    int* cnt = (int*)alloc((size_t)(B_G * N0) * 4);
    ushort* srcl = (ushort*)alloc((size_t)E_TOTAL * 2);
    int* valid1 = (int*)alloc((size_t)(B_G * N0) * 4);
    int* valid2 = (int*)alloc((size_t)(B_G * N0) * 4);
    float* score = (float*)alloc((size_t)(B_G * N0) * 4);
    float* gpart = (float*)alloc((size_t)3 * B_G * 256 * 4);

    setup_kernel<<<B_G + (3 * 32768 + 511) / 512, 512, 0, stream>>>(
        Wrel[0], Wroot[0], Wrel[1], Wroot[1], Wrel[2], Wroot[2],
        Bph, Bpl, es, ed, ipt, cnt, srcl);

    const size_t SLAB = (size_t)N0 * 32 * 4;   // 64 KB
    // L0
    aggregate0<<<4 * B_G, 1024, SLAB, stream>>>(x0, ipt, cnt, srcl, P1);
    transform_mfma<<<B_G * N0 / 128, 512, 0, stream>>>(
        P1, nullptr, x0, Bph, Bpl, brel[0], pvec[0], PA, score);
    pool_kernel<<<4 * B_G, 1024, SLAB, stream>>>(
        score, PA, gpart + (size_t)0 * B_G * 256,
        ipt, cnt, srcl, nullptr, valid1, P1, K1);

    // L1
    transform_mfma<<<B_G * N0 / 128, 512, 0, stream>>>(
        P1, PA, nullptr, Bph + 32768, Bpl + 32768, brel[1], pvec[1], PB, score);
    pool_kernel<<<4 * B_G, 1024, SLAB, stream>>>(
        score, PB, gpart + (size_t)1 * B_G * 256,
        ipt, cnt, srcl, valid1, valid2, P1, K2);

    // L2
    transform_mfma<<<B_G * N0 / 128, 512, 0, stream>>>(
        P1, PB, nullptr, Bph + 2 * 32768, Bpl + 2 * 32768, brel[2], pvec[2], PA, score);
    pool_kernel<<<4 * B_G, 1024, SLAB, stream>>>(
        score, PA, gpart + (size_t)2 * B_G * 256,
        ipt, cnt, srcl, valid2, nullptr, nullptr, K3);

    mlp_kernel<<<B_G, 128, 0, stream>>>(gpart, W1, b1, W2, b2, W3, b3, (float*)d_out);
}